// Round 12
// baseline (302.847 us; speedup 1.0000x reference)
//
#include <hip/hip_runtime.h>

// Problem constants: B=2, S=2048, D=1024, H=16, Hd=64
#define S_   2048
#define D_   1024

typedef __attribute__((ext_vector_type(8))) __bf16 bf16x8;
typedef __attribute__((ext_vector_type(4))) __bf16 bf16x4;
typedef __attribute__((ext_vector_type(4))) float f32x4;
typedef __attribute__((ext_vector_type(4))) float float4v;
typedef __attribute__((ext_vector_type(2))) unsigned int u32x2;
typedef __attribute__((ext_vector_type(4))) unsigned int u32x4;

// Workspace layout (in bf16/short elements)
#define XQ_OFF   0           // 4096x1024 bf16 inputs
#define XK_OFF   4194304
#define XV_OFF   8388608
#define WQT_OFF  12582912    // W^T 1024x1024 bf16, [n][k]
#define WKT_OFF  13631488
#define WVT_OFF  14680064
#define WOT_OFF  15728640
// Fragment-ordered tensors (produced by gemm epilogues, consumed by attn):
//  qhF[bh][rt 128][h 2][lane 64][e 8]   rt = 16-q-row block; PRE-SCALED
//  khF[bh][kt 32][f 8][lane 64][e 8]    f = m*2+half (QK^T A-operand frags)
//  vhF[bh][kt 32][fv 8][lane 64][e 8]   fv = n*2+kk   (PV B-operand frags)
#define QH_OFF   16777216
#define KH_OFF   20971520
#define VHT_OFF  25165824
#define CTX_OFF  29360128    // (B,S,D) bf16
#define WS_BYTES 67108864ULL

#if __has_builtin(__builtin_amdgcn_exp2f)
#define EXP2(x) __builtin_amdgcn_exp2f(x)
#else
#define EXP2(x) __expf((x) * 0.69314718056f)
#endif
#define QSCALE 0.1803368801f  // 0.125 * log2(e)

__device__ __forceinline__ unsigned short f2b(float f) {  // fp32->bf16 RNE
  unsigned u = __builtin_bit_cast(unsigned, f);
  u += 0x7fffu + ((u >> 16) & 1u);
  return (unsigned short)(u >> 16);
}
__device__ __forceinline__ float b2f(unsigned s) {
  return __builtin_bit_cast(float, s << 16);
}

// ------------- K0: merged fp32->bf16 convert (x: qkv) + weight transpose ----
__global__ __launch_bounds__(256) void cvt_all(const float* __restrict__ q,
    const float* __restrict__ k, const float* __restrict__ v,
    const float* __restrict__ wq, const float* __restrict__ wk,
    const float* __restrict__ wv, const float* __restrict__ wo,
    short* __restrict__ ws) {
  __shared__ float tile[32][33];
  int b = blockIdx.x, tid = threadIdx.x;
  if (b < 12288) {
    int y = b >> 12, x = b & 4095;
    const float* src = (y == 0) ? q : (y == 1) ? k : v;
    short* dst = ws + (size_t)y * 4194304;
    size_t t = (size_t)x * 256 + tid;
    float4v f = *(const float4v*)(src + t * 4);
    u32x2 p;
    p[0] = (unsigned)f2b(f[0]) | ((unsigned)f2b(f[1]) << 16);
    p[1] = (unsigned)f2b(f[2]) | ((unsigned)f2b(f[3]) << 16);
    *(u32x2*)(dst + t * 4) = p;
    return;
  }
  int b2 = b - 12288;            // weight transpose: 4096 blocks
  int z = b2 >> 10, rem = b2 & 1023;
  int by = rem >> 5, bx = rem & 31;
  const float* W = (z == 0) ? wq : (z == 1) ? wk : (z == 2) ? wv : wo;
  short* Wt = ws + WQT_OFF + (size_t)z * 1048576;
  int tx = tid & 31, ty = tid >> 5;  // 32 x 8
#pragma unroll
  for (int i = 0; i < 4; ++i)
    tile[ty + i * 8][tx] =
        W[(size_t)(by * 32 + ty + i * 8) * D_ + bx * 32 + tx];
  __syncthreads();
#pragma unroll
  for (int i = 0; i < 4; ++i)
    Wt[(size_t)(bx * 32 + ty + i * 8) * D_ + by * 32 + tx] =
        (short)f2b(tile[tx][ty + i * 8]);
}

// ---------------- K1/K3: bf16 GEMM, 128x128 tile, 2-phase ----------------
__device__ __forceinline__ void stage_tile(const short* __restrict__ g,
                                           short* l, int w, int lane) {
  int lrow = lane >> 3, lcol = (lane & 7) * 8;
#pragma unroll
  for (int c = 0; c < 4; ++c) {
    int seg = c * 4 + w;  // 0..15, 8 rows each
    const short* gp = g + (size_t)(seg * 8 + lrow) * 1024 + lcol;
    short* lp = l + seg * 512 + lane * 8;
    __builtin_amdgcn_global_load_lds(
        (const __attribute__((address_space(1))) void*)gp,
        (__attribute__((address_space(3))) void*)lp, 16, 0, 0);
  }
}

__global__ __launch_bounds__(256) void gemm_bf16(short* __restrict__ ws,
    const float* __restrict__ bq, const float* __restrict__ bk,
    const float* __restrict__ bv, const float* __restrict__ bo,
    float* __restrict__ out, int mode_base) {
  const int tid = threadIdx.x, lane = tid & 63, w = tid >> 6;
  const int wm = w >> 1, wn = w & 1;
  const int ln15 = lane & 15, g = lane >> 4;
  const int bm = blockIdx.y, bn = blockIdx.x;
  const int mode = (mode_base == 3) ? 3 : (int)blockIdx.z;

  const short* A; const short* Bt; const float* bias;
  if (mode == 0)      { A = ws + XQ_OFF;  Bt = ws + WQT_OFF; bias = bq; }
  else if (mode == 1) { A = ws + XK_OFF;  Bt = ws + WKT_OFF; bias = bk; }
  else if (mode == 2) { A = ws + XV_OFF;  Bt = ws + WVT_OFF; bias = bv; }
  else                { A = ws + CTX_OFF; Bt = ws + WOT_OFF; bias = bo; }

  __shared__ short smem[2][2][8192];   // [A/B][dbuf][128*64]
  short (*sA)[8192] = smem[0];
  short (*sB)[8192] = smem[1];

  f32x4 acc[4][4] = {};

  const short* Ab = A + (size_t)bm * 128 * 1024;
  const short* Bb = Bt + (size_t)bn * 128 * 1024;

  stage_tile(Ab, sA[0], w, lane);
  stage_tile(Bb, sB[0], w, lane);
  __syncthreads();

  int cur = 0;
#pragma unroll 1
  for (int kt = 0; kt < 16; ++kt) {
    if (kt < 15) {
      stage_tile(Ab + (kt + 1) * 64, sA[cur ^ 1], w, lane);
      stage_tile(Bb + (kt + 1) * 64, sB[cur ^ 1], w, lane);
    }
#pragma unroll
    for (int kk = 0; kk < 2; ++kk) {
      bf16x8 af[4], bfr[4];
#pragma unroll
      for (int m = 0; m < 4; ++m)
        af[m] = *(const bf16x8*)&sA[cur][(wm * 64 + m * 16 + ln15) * 64 + kk * 32 + g * 8];
#pragma unroll
      for (int n = 0; n < 4; ++n)
        bfr[n] = *(const bf16x8*)&sB[cur][(wn * 64 + n * 16 + ln15) * 64 + kk * 32 + g * 8];
#pragma unroll
      for (int m = 0; m < 4; ++m)
#pragma unroll
        for (int n = 0; n < 4; ++n)
          acc[m][n] = __builtin_amdgcn_mfma_f32_16x16x32_bf16(af[m], bfr[n], acc[m][n], 0, 0, 0);
    }
    __syncthreads();
    cur ^= 1;
  }

  float bb[4];
#pragma unroll
  for (int n = 0; n < 4; ++n) bb[n] = bias[bn * 128 + wn * 64 + n * 16 + ln15];

  if (mode == 3) {
#pragma unroll
    for (int m = 0; m < 4; ++m) {
      int row0 = bm * 128 + wm * 64 + m * 16 + g * 4;
#pragma unroll
      for (int n = 0; n < 4; ++n) {
        int col = bn * 128 + wn * 64 + n * 16 + ln15;
#pragma unroll
        for (int r = 0; r < 4; ++r)
          out[(size_t)(row0 + r) * 1024 + col] = acc[m][n][r] + bb[n];
      }
    }
    return;
  }

  // ---- modes 0/1/2: stage C tile to LDS, then write FRAGMENT-ORDERED ----
  float sc = (mode == 0) ? QSCALE : 1.0f;
  short (*tile)[136] = (short(*)[136])smem;  // 128x136 bf16
#pragma unroll
  for (int m = 0; m < 4; ++m)
#pragma unroll
    for (int n = 0; n < 4; ++n)
#pragma unroll
      for (int r = 0; r < 4; ++r)
        tile[wm * 64 + m * 16 + g * 4 + r][wn * 64 + n * 16 + ln15] =
            (short)f2b((acc[m][n][r] + bb[n]) * sc);
  __syncthreads();

  const int bq_ = bm >> 4;       // batch of this s-panel
  const int sml = bm & 15;       // batch-LOCAL s-panel index (r11 bugfix)
  if (mode == 0) {
    // qhF: frag (rt, h): lane l -> Q[rt*16+(l&15)][h*32+(l>>4)*8+e]
    int h_out = tid >> 7, rt = (tid >> 4) & 7, h = (tid >> 3) & 1, sub = tid & 7;
    int bh = bq_ * 16 + bn * 2 + h_out;
    size_t base = QH_OFF + (((size_t)bh * 128 + sml * 8 + rt) * 2 + h) * 512;
#pragma unroll
    for (int i = 0; i < 8; ++i) {
      int l = sub * 8 + i;
      u32x4 v = *(const u32x4*)&tile[rt * 16 + (l & 15)]
                                    [h_out * 64 + h * 32 + (l >> 4) * 8];
      *(u32x4*)&ws[base + l * 8] = v;
    }
  } else if (mode == 1) {
    // khF: frag f=m*2+half: lane l -> K[kt*64+m*16+(l&15)][half*32+(l>>4)*8+e]
    int kt_l = tid >> 7, h_out = (tid >> 6) & 1, f = (tid >> 3) & 7, sub = tid & 7;
    int bh = bq_ * 16 + bn * 2 + h_out;
    size_t base = KH_OFF + (((size_t)bh * 32 + sml * 2 + kt_l) * 8 + f) * 512;
#pragma unroll
    for (int i = 0; i < 8; ++i) {
      int l = sub * 8 + i;
      u32x4 v = *(const u32x4*)&tile[kt_l * 64 + (f >> 1) * 16 + (l & 15)]
                                    [h_out * 64 + (f & 1) * 32 + (l >> 4) * 8];
      *(u32x4*)&ws[base + l * 8] = v;
    }
  } else {
    // vhF: frag fv=n*2+kk: lane l -> V^T[hd=n*16+(l&15)][s=kt*64+kk*32+(l>>4)*8+e]
    //      (gather: e runs over tile ROWS)
    int kt_l = tid >> 7, h_out = (tid >> 6) & 1, fv = (tid >> 3) & 7, sub = tid & 7;
    int bh = bq_ * 16 + bn * 2 + h_out;
    size_t base = VHT_OFF + (((size_t)bh * 32 + sml * 2 + kt_l) * 8 + fv) * 512;
#pragma unroll
    for (int i = 0; i < 8; ++i) {
      int l = sub * 8 + i;
      int hd = h_out * 64 + (fv >> 1) * 16 + (l & 15);
      int s0 = kt_l * 64 + (fv & 1) * 32 + (l >> 4) * 8;
      u32x4 pk;
#pragma unroll
      for (int e2 = 0; e2 < 4; ++e2) {
        unsigned lo = (unsigned short)tile[s0 + e2 * 2][hd];
        unsigned hi = (unsigned short)tile[s0 + e2 * 2 + 1][hd];
        pk[e2] = lo | (hi << 16);
      }
      *(u32x4*)&ws[base + l * 8] = pk;
    }
  }
}

// ---------------- K2: fused attention, register fragments, NO barriers ----
// K/V/Q pre-laid in MFMA fragment order -> each kt tile = 8 contiguous
// dwordx4 wave-loads into registers (1-2 TA tx each, L2-resident). No LDS
// staging, no barriers. LDS = Pbig only (rows wave-private). Stores: after
// each 4-kt super-iter, 16 rows x 1KB wave-contiguous f32 runs issued with
// NO waits -- next super-iter's compute overlaps the drain.
__global__ __launch_bounds__(512) void attn_k(short* __restrict__ ws,
                                              float* __restrict__ attn) {
  const int tid = threadIdx.x, lane = tid & 63, w = tid >> 6;  // 8 waves
  const int ln15 = lane & 15, g = lane >> 4;
  int bid = blockIdx.x;                  // 512 blocks
  int qt = (bid >> 3) & 15;              // 16 q-tiles of 128 rows
  int bh = (bid & 7) + 8 * (bid >> 7);   // XCD-affine: 4 bh per XCD
  const int q0 = qt * 128;

  const short* qhF = ws + QH_OFF + (((size_t)bh * 128 + qt * 8 + w) * 2) * 512;
  const short* khF = ws + KH_OFF + (size_t)bh * 131072;
  const short* vhF = ws + VHT_OFF + (size_t)bh * 131072;

  __shared__ short Pbig[128][264];  // 4-kt P buffer; rows wave-private

  bf16x8 qf0 = *(const bf16x8*)&qhF[lane * 8];
  bf16x8 qf1 = *(const bf16x8*)&qhF[512 + lane * 8];

  // ---- pass 1: softmax denominators (no LDS, no barriers) ----
  float ps0 = 0.f, ps1 = 0.f;
#pragma unroll 1
  for (int kt = 0; kt < 32; ++kt) {
    const short* kb = khF + kt * 4096 + lane * 8;
    bf16x8 ka[8];
#pragma unroll
    for (int f = 0; f < 8; ++f) ka[f] = *(const bf16x8*)&kb[f * 512];
#pragma unroll
    for (int m = 0; m < 4; ++m) {
      f32x4 c = {0.f, 0.f, 0.f, 0.f};
      c = __builtin_amdgcn_mfma_f32_16x16x32_bf16(ka[m * 2], qf0, c, 0, 0, 0);
      c = __builtin_amdgcn_mfma_f32_16x16x32_bf16(ka[m * 2 + 1], qf1, c, 0, 0, 0);
      ps0 += EXP2(c[0]) + EXP2(c[1]);
      ps1 += EXP2(c[2]) + EXP2(c[3]);
    }
  }
  float ps = ps0 + ps1;
  ps += __shfl_xor(ps, 16, 64);  // reduce the 4 k-groups (same q col)
  ps += __shfl_xor(ps, 32, 64);
  float ri = 1.0f / ps;

  // ---- pass 2: 4-kt super-iterations ----
  f32x4 cacc[4] = {};
#pragma unroll 1
  for (int s = 0; s < 8; ++s) {
#pragma unroll
    for (int j = 0; j < 4; ++j) {
      const int kt = s * 4 + j;
      const short* kb = khF + kt * 4096 + lane * 8;
      // QK^T (swapped): lane holds P[q=ln15][k=kt*64+m*16+g*4+r]
#pragma unroll
      for (int m = 0; m < 4; ++m) {
        bf16x8 ka0 = *(const bf16x8*)&kb[(m * 2) * 512];
        bf16x8 ka1 = *(const bf16x8*)&kb[(m * 2 + 1) * 512];
        f32x4 c = {0.f, 0.f, 0.f, 0.f};
        c = __builtin_amdgcn_mfma_f32_16x16x32_bf16(ka0, qf0, c, 0, 0, 0);
        c = __builtin_amdgcn_mfma_f32_16x16x32_bf16(ka1, qf1, c, 0, 0, 0);
        bf16x4 pb;
        pb[0] = (__bf16)(EXP2(c[0]) * ri);
        pb[1] = (__bf16)(EXP2(c[1]) * ri);
        pb[2] = (__bf16)(EXP2(c[2]) * ri);
        pb[3] = (__bf16)(EXP2(c[3]) * ri);
        *(bf16x4*)&Pbig[w * 16 + ln15][j * 64 + m * 16 + g * 4] = pb;
      }
      // PV: V fragments from registers (contiguous loads)
      const short* vb_ = vhF + kt * 4096 + lane * 8;
      bf16x8 vb[8];
#pragma unroll
      for (int f = 0; f < 8; ++f) vb[f] = *(const bf16x8*)&vb_[f * 512];
#pragma unroll
      for (int kk = 0; kk < 2; ++kk) {
        bf16x8 pa =
            *(const bf16x8*)&Pbig[w * 16 + ln15][j * 64 + kk * 32 + g * 8];
#pragma unroll
        for (int n = 0; n < 4; ++n)
          cacc[n] = __builtin_amdgcn_mfma_f32_16x16x32_bf16(
              pa, vb[n * 2 + kk], cacc[n], 0, 0, 0);
      }
    }

    // store phase: 16 rows x 1KB wave-contiguous f32, no waits (overlaps
    // with the next super-iteration's compute)
    float* ab = attn + ((size_t)(bh * 2048 + q0 + w * 16)) * 2048 + s * 256 +
                lane * 4;
#pragma unroll
    for (int r = 0; r < 16; ++r) {
      u32x2 pv = *(const u32x2*)&Pbig[w * 16 + r][lane * 4];
      float4v o;
      o[0] = b2f(pv[0] & 0xffffu);
      o[1] = b2f(pv[0] >> 16);
      o[2] = b2f(pv[1] & 0xffffu);
      o[3] = b2f(pv[1] >> 16);
      *(float4v*)(ab + (size_t)r * 2048) = o;
    }
  }

  // ctx epilogue -> (B,S,D) bf16, repacked via Pbig slice to 128B rows
  {
    short* Pw = &Pbig[w * 16][0];
#pragma unroll
    for (int n = 0; n < 4; ++n)
#pragma unroll
      for (int r = 0; r < 4; ++r)
        Pw[(g * 4 + r) * 264 + n * 16 + ln15] = (short)f2b(cacc[n][r]);
    int b = bh >> 4, h = bh & 15;
    int row = lane >> 3, col = (lane & 7) * 8;
#pragma unroll
    for (int i = 0; i < 2; ++i) {
      int q = q0 + w * 16 + i * 8 + row;
      u32x4 pk = *(const u32x4*)&Pw[(i * 8 + row) * 264 + col];
      *(u32x4*)&ws[CTX_OFF + ((size_t)(b * 2048 + q)) * 1024 + h * 64 + col] = pk;
    }
  }
}

extern "C" void kernel_launch(void* const* d_in, const int* in_sizes, int n_in,
                              void* d_out, int out_size, void* d_ws, size_t ws_size,
                              hipStream_t stream) {
  const float* q  = (const float*)d_in[0];
  const float* k  = (const float*)d_in[1];
  const float* v  = (const float*)d_in[2];
  const float* wq = (const float*)d_in[3];
  const float* bq = (const float*)d_in[4];
  const float* wk = (const float*)d_in[5];
  const float* bk = (const float*)d_in[6];
  const float* wv = (const float*)d_in[7];
  const float* bv = (const float*)d_in[8];
  const float* wo = (const float*)d_in[9];
  const float* bo = (const float*)d_in[10];
  float* out  = (float*)d_out;
  float* attn = out + 4194304;  // out (2,2048,1024) then attn (2,16,2048,2048)
  short* ws = (short*)d_ws;
  if (ws_size < WS_BYTES) return;  // need 64 MB scratch

  cvt_all<<<dim3(16384), 256, 0, stream>>>(q, k, v, wq, wk, wv, wo, ws);
  gemm_bf16<<<dim3(8, 32, 3), 256, 0, stream>>>(ws, bq, bk, bv, bo, out, 0);
  attn_k<<<dim3(512), 512, 0, stream>>>(ws, attn);
  gemm_bf16<<<dim3(8, 32, 1), 256, 0, stream>>>(ws, bq, bk, bv, bo, out, 3);
}

// Round 13
// 295.512 us; speedup vs baseline: 1.0248x; 1.0248x over previous
//
#include <hip/hip_runtime.h>

// Problem constants: B=2, S=2048, D=1024, H=16, Hd=64
#define S_   2048
#define D_   1024

typedef __attribute__((ext_vector_type(8))) __bf16 bf16x8;
typedef __attribute__((ext_vector_type(4))) __bf16 bf16x4;
typedef __attribute__((ext_vector_type(4))) float f32x4;
typedef __attribute__((ext_vector_type(4))) float float4v;
typedef __attribute__((ext_vector_type(2))) unsigned int u32x2;
typedef __attribute__((ext_vector_type(4))) unsigned int u32x4;

// Workspace layout (in bf16/short elements)
#define XQ_OFF   0           // 4096x1024 bf16 inputs
#define XK_OFF   4194304
#define XV_OFF   8388608
#define WQT_OFF  12582912    // W^T 1024x1024 bf16, [n][k]
#define WKT_OFF  13631488
#define WVT_OFF  14680064
#define WOT_OFF  15728640
// Fragment-ordered tensors (produced by gemm epilogues, consumed by attn):
//  qhF[bh][rt 128][h 2][lane 64][e 8]   rt = 16-q-row block; PRE-SCALED
//  khF[bh][kt 32][f 8][lane 64][e 8]    f = m*2+half (QK^T A-operand frags)
//  vhF[bh][kt 32][fv 8][lane 64][e 8]   fv = n*2+kk   (PV B-operand frags)
#define QH_OFF   16777216
#define KH_OFF   20971520
#define VHT_OFF  25165824
#define CTX_OFF  29360128    // (B,S,D) bf16
#define WS_BYTES 67108864ULL

#if __has_builtin(__builtin_amdgcn_exp2f)
#define EXP2(x) __builtin_amdgcn_exp2f(x)
#else
#define EXP2(x) __expf((x) * 0.69314718056f)
#endif
#define QSCALE 0.1803368801f  // 0.125 * log2(e)

__device__ __forceinline__ unsigned short f2b(float f) {  // fp32->bf16 RNE
  unsigned u = __builtin_bit_cast(unsigned, f);
  u += 0x7fffu + ((u >> 16) & 1u);
  return (unsigned short)(u >> 16);
}
__device__ __forceinline__ float b2f(unsigned s) {
  return __builtin_bit_cast(float, s << 16);
}

// ------------- K0: merged fp32->bf16 convert (x: qkv) + weight transpose ----
__global__ __launch_bounds__(256) void cvt_all(const float* __restrict__ q,
    const float* __restrict__ k, const float* __restrict__ v,
    const float* __restrict__ wq, const float* __restrict__ wk,
    const float* __restrict__ wv, const float* __restrict__ wo,
    short* __restrict__ ws) {
  __shared__ float tile[32][33];
  int b = blockIdx.x, tid = threadIdx.x;
  if (b < 12288) {
    int y = b >> 12, x = b & 4095;
    const float* src = (y == 0) ? q : (y == 1) ? k : v;
    short* dst = ws + (size_t)y * 4194304;
    size_t t = (size_t)x * 256 + tid;
    float4v f = *(const float4v*)(src + t * 4);
    u32x2 p;
    p[0] = (unsigned)f2b(f[0]) | ((unsigned)f2b(f[1]) << 16);
    p[1] = (unsigned)f2b(f[2]) | ((unsigned)f2b(f[3]) << 16);
    *(u32x2*)(dst + t * 4) = p;
    return;
  }
  int b2 = b - 12288;            // weight transpose: 4096 blocks
  int z = b2 >> 10, rem = b2 & 1023;
  int by = rem >> 5, bx = rem & 31;
  const float* W = (z == 0) ? wq : (z == 1) ? wk : (z == 2) ? wv : wo;
  short* Wt = ws + WQT_OFF + (size_t)z * 1048576;
  int tx = tid & 31, ty = tid >> 5;  // 32 x 8
#pragma unroll
  for (int i = 0; i < 4; ++i)
    tile[ty + i * 8][tx] =
        W[(size_t)(by * 32 + ty + i * 8) * D_ + bx * 32 + tx];
  __syncthreads();
#pragma unroll
  for (int i = 0; i < 4; ++i)
    Wt[(size_t)(bx * 32 + ty + i * 8) * D_ + by * 32 + tx] =
        (short)f2b(tile[tx][ty + i * 8]);
}

// ---------------- K1/K3: bf16 GEMM, 128x128 tile, 2-phase ----------------
__device__ __forceinline__ void stage_tile(const short* __restrict__ g,
                                           short* l, int w, int lane) {
  int lrow = lane >> 3, lcol = (lane & 7) * 8;
#pragma unroll
  for (int c = 0; c < 4; ++c) {
    int seg = c * 4 + w;  // 0..15, 8 rows each
    const short* gp = g + (size_t)(seg * 8 + lrow) * 1024 + lcol;
    short* lp = l + seg * 512 + lane * 8;
    __builtin_amdgcn_global_load_lds(
        (const __attribute__((address_space(1))) void*)gp,
        (__attribute__((address_space(3))) void*)lp, 16, 0, 0);
  }
}

__global__ __launch_bounds__(256) void gemm_bf16(short* __restrict__ ws,
    const float* __restrict__ bq, const float* __restrict__ bk,
    const float* __restrict__ bv, const float* __restrict__ bo,
    float* __restrict__ out, int mode_base) {
  const int tid = threadIdx.x, lane = tid & 63, w = tid >> 6;
  const int wm = w >> 1, wn = w & 1;
  const int ln15 = lane & 15, g = lane >> 4;
  const int bm = blockIdx.y, bn = blockIdx.x;
  const int mode = (mode_base == 3) ? 3 : (int)blockIdx.z;

  const short* A; const short* Bt; const float* bias;
  if (mode == 0)      { A = ws + XQ_OFF;  Bt = ws + WQT_OFF; bias = bq; }
  else if (mode == 1) { A = ws + XK_OFF;  Bt = ws + WKT_OFF; bias = bk; }
  else if (mode == 2) { A = ws + XV_OFF;  Bt = ws + WVT_OFF; bias = bv; }
  else                { A = ws + CTX_OFF; Bt = ws + WOT_OFF; bias = bo; }

  __shared__ short smem[2][2][8192];   // [A/B][dbuf][128*64]
  short (*sA)[8192] = smem[0];
  short (*sB)[8192] = smem[1];

  f32x4 acc[4][4] = {};

  const short* Ab = A + (size_t)bm * 128 * 1024;
  const short* Bb = Bt + (size_t)bn * 128 * 1024;

  stage_tile(Ab, sA[0], w, lane);
  stage_tile(Bb, sB[0], w, lane);
  __syncthreads();

  int cur = 0;
#pragma unroll 1
  for (int kt = 0; kt < 16; ++kt) {
    if (kt < 15) {
      stage_tile(Ab + (kt + 1) * 64, sA[cur ^ 1], w, lane);
      stage_tile(Bb + (kt + 1) * 64, sB[cur ^ 1], w, lane);
    }
#pragma unroll
    for (int kk = 0; kk < 2; ++kk) {
      bf16x8 af[4], bfr[4];
#pragma unroll
      for (int m = 0; m < 4; ++m)
        af[m] = *(const bf16x8*)&sA[cur][(wm * 64 + m * 16 + ln15) * 64 + kk * 32 + g * 8];
#pragma unroll
      for (int n = 0; n < 4; ++n)
        bfr[n] = *(const bf16x8*)&sB[cur][(wn * 64 + n * 16 + ln15) * 64 + kk * 32 + g * 8];
#pragma unroll
      for (int m = 0; m < 4; ++m)
#pragma unroll
        for (int n = 0; n < 4; ++n)
          acc[m][n] = __builtin_amdgcn_mfma_f32_16x16x32_bf16(af[m], bfr[n], acc[m][n], 0, 0, 0);
    }
    __syncthreads();
    cur ^= 1;
  }

  float bb[4];
#pragma unroll
  for (int n = 0; n < 4; ++n) bb[n] = bias[bn * 128 + wn * 64 + n * 16 + ln15];

  if (mode == 3) {
#pragma unroll
    for (int m = 0; m < 4; ++m) {
      int row0 = bm * 128 + wm * 64 + m * 16 + g * 4;
#pragma unroll
      for (int n = 0; n < 4; ++n) {
        int col = bn * 128 + wn * 64 + n * 16 + ln15;
#pragma unroll
        for (int r = 0; r < 4; ++r)
          out[(size_t)(row0 + r) * 1024 + col] = acc[m][n][r] + bb[n];
      }
    }
    return;
  }

  // ---- modes 0/1/2: stage C tile to LDS, then write FRAGMENT-ORDERED ----
  float sc = (mode == 0) ? QSCALE : 1.0f;
  short (*tile)[136] = (short(*)[136])smem;  // 128x136 bf16
#pragma unroll
  for (int m = 0; m < 4; ++m)
#pragma unroll
    for (int n = 0; n < 4; ++n)
#pragma unroll
      for (int r = 0; r < 4; ++r)
        tile[wm * 64 + m * 16 + g * 4 + r][wn * 64 + n * 16 + ln15] =
            (short)f2b((acc[m][n][r] + bb[n]) * sc);
  __syncthreads();

  const int bq_ = bm >> 4;       // batch of this s-panel
  const int sml = bm & 15;       // batch-LOCAL s-panel index
  if (mode == 0) {
    // qhF: frag (rt, h): lane l -> Q[rt*16+(l&15)][h*32+(l>>4)*8+e]
    int h_out = tid >> 7, rt = (tid >> 4) & 7, h = (tid >> 3) & 1, sub = tid & 7;
    int bh = bq_ * 16 + bn * 2 + h_out;
    size_t base = QH_OFF + (((size_t)bh * 128 + sml * 8 + rt) * 2 + h) * 512;
#pragma unroll
    for (int i = 0; i < 8; ++i) {
      int l = sub * 8 + i;
      u32x4 v = *(const u32x4*)&tile[rt * 16 + (l & 15)]
                                    [h_out * 64 + h * 32 + (l >> 4) * 8];
      *(u32x4*)&ws[base + l * 8] = v;
    }
  } else if (mode == 1) {
    // khF: frag f=m*2+half: lane l -> K[kt*64+m*16+(l&15)][half*32+(l>>4)*8+e]
    int kt_l = tid >> 7, h_out = (tid >> 6) & 1, f = (tid >> 3) & 7, sub = tid & 7;
    int bh = bq_ * 16 + bn * 2 + h_out;
    size_t base = KH_OFF + (((size_t)bh * 32 + sml * 2 + kt_l) * 8 + f) * 512;
#pragma unroll
    for (int i = 0; i < 8; ++i) {
      int l = sub * 8 + i;
      u32x4 v = *(const u32x4*)&tile[kt_l * 64 + (f >> 1) * 16 + (l & 15)]
                                    [h_out * 64 + (f & 1) * 32 + (l >> 4) * 8];
      *(u32x4*)&ws[base + l * 8] = v;
    }
  } else {
    // vhF: frag fv=n*2+kk: lane l -> V^T[hd=n*16+(l&15)][s=kt*64+kk*32+(l>>4)*8+e]
    int kt_l = tid >> 7, h_out = (tid >> 6) & 1, fv = (tid >> 3) & 7, sub = tid & 7;
    int bh = bq_ * 16 + bn * 2 + h_out;
    size_t base = VHT_OFF + (((size_t)bh * 32 + sml * 2 + kt_l) * 8 + fv) * 512;
#pragma unroll
    for (int i = 0; i < 8; ++i) {
      int l = sub * 8 + i;
      int hd = h_out * 64 + (fv >> 1) * 16 + (l & 15);
      int s0 = kt_l * 64 + (fv & 1) * 32 + (l >> 4) * 8;
      u32x4 pk;
#pragma unroll
      for (int e2 = 0; e2 < 4; ++e2) {
        unsigned lo = (unsigned short)tile[s0 + e2 * 2][hd];
        unsigned hi = (unsigned short)tile[s0 + e2 * 2 + 1][hd];
        pk[e2] = lo | (hi << 16);
      }
      *(u32x4*)&ws[base + l * 8] = pk;
    }
  }
}

// ---------------- K2: fused attention, full-row single-pass ----------
// Per (bh, 128-q tile) block: 8 groups of 16 q rows. Per group, the FULL
// 2048-k P row-set is computed into Prow LDS (waves split by kt), rows are
// then stored as 8KB SEQUENTIAL f32 runs (2 adjacent rows per wave = 16KB).
// Fill-kernel evidence: >=4KB runs reach ~6.7 TB/s; r8's 256B got 2.9.
// Full row resident => single pass (no denominator prepass): sum unnorm
// exp2 via shfl + rs[], normalize at store; PV uses unnorm P split by
// (n-frag x k-half) across waves, partials pair-reduced via LDS, scaled by
// 1/rowsum at the ctx write. QK^T MFMAs drop 33%, exp2 and K-reads halve.
__global__ __launch_bounds__(512, 4) void attn_k(short* __restrict__ ws,
                                                 float* __restrict__ attn) {
  const int tid = threadIdx.x, lane = tid & 63, w = tid >> 6;  // 8 waves
  const int ln15 = lane & 15, g = lane >> 4;
  int bid = blockIdx.x;                  // 512 blocks
  int qt = (bid >> 3) & 15;              // 16 q-tiles of 128 rows
  int bh = (bid & 7) + 8 * (bid >> 7);   // XCD-affine: 4 bh per XCD
  const int q0 = qt * 128;

  const short* qhF = ws + QH_OFF + (size_t)bh * 131072;
  const short* khF = ws + KH_OFF + (size_t)bh * 131072;
  const short* vhF = ws + VHT_OFF + (size_t)bh * 131072;

  __shared__ short Prow[16][2050];   // 65.6 KB; stride 1025 dwords (bank+1/row)
  __shared__ float rs[8][16];        // per-wave partial row sums
  __shared__ float ritot[16];        // 1/rowsum, published by store phase
  __shared__ float4v pbuf[4][64];    // PV partial hand-off (waves 4-7 -> 0-3)

  const int n_pv = w & 3, kh16 = (w >> 2) * 16, w4 = w * 4;
  const int b_ = bh >> 4, h_ = bh & 15;

#pragma unroll 1
  for (int qg = 0; qg < 8; ++qg) {
    const int rt = qt * 8 + qg;
    const short* qb = qhF + (size_t)rt * 1024;
    bf16x8 qf0 = *(const bf16x8*)&qb[lane * 8];
    bf16x8 qf1 = *(const bf16x8*)&qb[512 + lane * 8];

    // ---- QK^T for this wave's 4 kt: unnormalized exp2 -> Prow ----
    float ps0 = 0.f, ps1 = 0.f;
#pragma unroll
    for (int j = 0; j < 4; ++j) {
      const int kt = w4 + j;
      const short* kb = khF + kt * 4096 + lane * 8;
#pragma unroll
      for (int m = 0; m < 4; ++m) {
        bf16x8 ka0 = *(const bf16x8*)&kb[(m * 2) * 512];
        bf16x8 ka1 = *(const bf16x8*)&kb[(m * 2 + 1) * 512];
        f32x4 c = {0.f, 0.f, 0.f, 0.f};
        c = __builtin_amdgcn_mfma_f32_16x16x32_bf16(ka0, qf0, c, 0, 0, 0);
        c = __builtin_amdgcn_mfma_f32_16x16x32_bf16(ka1, qf1, c, 0, 0, 0);
        float e0 = EXP2(c[0]), e1 = EXP2(c[1]);
        float e2 = EXP2(c[2]), e3 = EXP2(c[3]);
        ps0 += e0 + e1;
        ps1 += e2 + e3;
        bf16x4 pb;
        pb[0] = (__bf16)e0; pb[1] = (__bf16)e1;
        pb[2] = (__bf16)e2; pb[3] = (__bf16)e3;
        *(bf16x4*)&Prow[ln15][kt * 64 + m * 16 + g * 4] = pb;
      }
    }
    float ps = ps0 + ps1;
    ps += __shfl_xor(ps, 16, 64);  // reduce over the 4 g-groups (same row)
    ps += __shfl_xor(ps, 32, 64);
    if (lane < 16) rs[w][lane] = ps;

    asm volatile("s_waitcnt lgkmcnt(0)" ::: "memory");
    __builtin_amdgcn_s_barrier();  // B1: Prow + rs published

    // ---- PV: this wave's n-fragment over its k-half (unnormalized) ----
    f32x4 cacc = {0.f, 0.f, 0.f, 0.f};
#pragma unroll
    for (int t2 = 0; t2 < 16; ++t2) {
      const int kt = kh16 + t2;
      const short* vb_ = vhF + kt * 4096 + lane * 8;
#pragma unroll
      for (int kk = 0; kk < 2; ++kk) {
        bf16x8 pa = *(const bf16x8*)&Prow[ln15][kt * 64 + kk * 32 + g * 8];
        bf16x8 vb = *(const bf16x8*)&vb_[(n_pv * 2 + kk) * 512];
        cacc = __builtin_amdgcn_mfma_f32_16x16x32_bf16(pa, vb, cacc, 0, 0, 0);
      }
    }

    // ---- attn stores: 2 adjacent rows per wave, 8KB sequential each ----
#pragma unroll
    for (int rr = 0; rr < 2; ++rr) {
      const int r = w * 2 + rr;
      float s = 0.f;
#pragma unroll
      for (int ww = 0; ww < 8; ++ww) s += rs[ww][r];  // broadcast reads
      const float ri = 1.0f / s;
      if (lane == 0) ritot[r] = ri;
      float* ab = attn +
                  ((size_t)(bh * 2048 + q0 + qg * 16 + r)) * 2048 + lane * 4;
#pragma unroll
      for (int c = 0; c < 8; ++c) {
        u32x2 pv = *(const u32x2*)&Prow[r][c * 256 + lane * 4];
        float4v o;
        o[0] = b2f(pv[0] & 0xffffu) * ri;
        o[1] = b2f(pv[0] >> 16) * ri;
        o[2] = b2f(pv[1] & 0xffffu) * ri;
        o[3] = b2f(pv[1] >> 16) * ri;
        *(float4v*)(ab + c * 256) = o;
      }
    }

    // ---- PV partial hand-off + ctx write ----
    if (w >= 4) pbuf[w - 4][lane] = cacc;
    asm volatile("s_waitcnt lgkmcnt(0)" ::: "memory");
    __builtin_amdgcn_s_barrier();  // B2: pbuf + ritot published

    if (w < 4) {
      float4v oth = pbuf[w][lane];
#pragma unroll
      for (int rr = 0; rr < 4; ++rr) {
        int qrow = q0 + qg * 16 + g * 4 + rr;
        float val = (cacc[rr] + oth[rr]) * ritot[g * 4 + rr];
        ws[CTX_OFF + ((size_t)(b_ * 2048 + qrow)) * 1024 + h_ * 64 +
           w * 16 + ln15] = (short)f2b(val);
      }
    }
    // no third barrier: next qg's Prow/rs writers are safe (all Prow reads
    // retired via lgkmcnt before each wave reached B2; post-B2 readers only
    // touch pbuf/ritot, which next qg rewrites only after the NEXT B1/B2).
  }
}

extern "C" void kernel_launch(void* const* d_in, const int* in_sizes, int n_in,
                              void* d_out, int out_size, void* d_ws, size_t ws_size,
                              hipStream_t stream) {
  const float* q  = (const float*)d_in[0];
  const float* k  = (const float*)d_in[1];
  const float* v  = (const float*)d_in[2];
  const float* wq = (const float*)d_in[3];
  const float* bq = (const float*)d_in[4];
  const float* wk = (const float*)d_in[5];
  const float* bk = (const float*)d_in[6];
  const float* wv = (const float*)d_in[7];
  const float* bv = (const float*)d_in[8];
  const float* wo = (const float*)d_in[9];
  const float* bo = (const float*)d_in[10];
  float* out  = (float*)d_out;
  float* attn = out + 4194304;  // out (2,2048,1024) then attn (2,16,2048,2048)
  short* ws = (short*)d_ws;
  if (ws_size < WS_BYTES) return;  // need 64 MB scratch

  cvt_all<<<dim3(16384), 256, 0, stream>>>(q, k, v, wq, wk, wv, wo, ws);
  gemm_bf16<<<dim3(8, 32, 3), 256, 0, stream>>>(ws, bq, bk, bv, bo, out, 0);
  attn_k<<<dim3(512), 512, 0, stream>>>(ws, attn);
  gemm_bf16<<<dim3(8, 32, 1), 256, 0, stream>>>(ws, bq, bk, bv, bo, out, 3);
}

// Round 14
// 268.727 us; speedup vs baseline: 1.1270x; 1.0997x over previous
//
#include <hip/hip_runtime.h>

// Problem constants: B=2, S=2048, D=1024, H=16, Hd=64
#define S_   2048
#define D_   1024

typedef __attribute__((ext_vector_type(8))) __bf16 bf16x8;
typedef __attribute__((ext_vector_type(4))) __bf16 bf16x4;
typedef __attribute__((ext_vector_type(4))) float f32x4;
typedef __attribute__((ext_vector_type(4))) float float4v;
typedef __attribute__((ext_vector_type(2))) unsigned int u32x2;
typedef __attribute__((ext_vector_type(4))) unsigned int u32x4;

// Workspace layout (in bf16/short elements)
#define XQ_OFF   0           // 4096x1024 bf16 inputs
#define XK_OFF   4194304
#define XV_OFF   8388608
#define WQT_OFF  12582912    // W^T 1024x1024 bf16, [n][k]
#define WKT_OFF  13631488
#define WVT_OFF  14680064
#define WOT_OFF  15728640
#define QH_OFF   16777216    // (B,H,S,Hd) bf16, PRE-SCALED by log2e/8
#define KH_OFF   20971520    // (B,H,S,Hd) bf16
#define VHT_OFF  25165824    // (B,H)(sblk 16)(hd 64)(s 128) bf16 blocked V^T
#define CTX_OFF  29360128    // (B,S,D) bf16
#define WS_BYTES 67108864ULL

#if __has_builtin(__builtin_amdgcn_exp2f)
#define EXP2(x) __builtin_amdgcn_exp2f(x)
#else
#define EXP2(x) __expf((x) * 0.69314718056f)
#endif
#define QSCALE 0.1803368801f  // 0.125 * log2(e)

__device__ __forceinline__ unsigned short f2b(float f) {  // fp32->bf16 RNE
  unsigned u = __builtin_bit_cast(unsigned, f);
  u += 0x7fffu + ((u >> 16) & 1u);
  return (unsigned short)(u >> 16);
}
__device__ __forceinline__ float b2f(unsigned s) {
  return __builtin_bit_cast(float, s << 16);
}

// ---------------- K0a: fp32 -> bf16 convert for q,k,v ----------------
__global__ __launch_bounds__(256) void cvt_qkv(const float* __restrict__ q,
    const float* __restrict__ k, const float* __restrict__ v,
    short* __restrict__ ws) {
  const float* src = (blockIdx.y == 0) ? q : (blockIdx.y == 1) ? k : v;
  short* dst = ws + (size_t)blockIdx.y * 4194304;
  size_t t = (size_t)blockIdx.x * 256 + threadIdx.x;   // 1,048,576 threads
  float4v f = *(const float4v*)(src + t * 4);
  u32x2 p;
  p[0] = (unsigned)f2b(f[0]) | ((unsigned)f2b(f[1]) << 16);
  p[1] = (unsigned)f2b(f[2]) | ((unsigned)f2b(f[3]) << 16);
  *(u32x2*)(dst + t * 4) = p;
}

// ------------- K0b: weights fp32 (K x N) -> bf16 W^T (N x K) -------------
__global__ __launch_bounds__(256) void cvt_wt(const float* __restrict__ wq,
    const float* __restrict__ wk, const float* __restrict__ wv,
    const float* __restrict__ wo, short* __restrict__ ws) {
  __shared__ float tile[32][33];
  int z = blockIdx.z;
  const float* W = (z == 0) ? wq : (z == 1) ? wk : (z == 2) ? wv : wo;
  short* Wt = ws + WQT_OFF + (size_t)z * 1048576;
  int tx = threadIdx.x, ty = threadIdx.y;  // 32 x 8
#pragma unroll
  for (int i = 0; i < 4; ++i)
    tile[ty + i * 8][tx] =
        W[(size_t)(blockIdx.y * 32 + ty + i * 8) * D_ + blockIdx.x * 32 + tx];
  __syncthreads();
#pragma unroll
  for (int i = 0; i < 4; ++i)
    Wt[(size_t)(blockIdx.x * 32 + ty + i * 8) * D_ + blockIdx.y * 32 + tx] =
        (short)f2b(tile[tx][ty + i * 8]);
}

// ---------------- K1/K3: bf16 GEMM, 128x128 tile, 2-phase ----------------
__device__ __forceinline__ void stage_tile(const short* __restrict__ g,
                                           short* l, int w, int lane) {
  int lrow = lane >> 3, lcol = (lane & 7) * 8;
#pragma unroll
  for (int c = 0; c < 4; ++c) {
    int seg = c * 4 + w;  // 0..15, 8 rows each
    const short* gp = g + (size_t)(seg * 8 + lrow) * 1024 + lcol;
    short* lp = l + seg * 512 + lane * 8;
    __builtin_amdgcn_global_load_lds(
        (const __attribute__((address_space(1))) void*)gp,
        (__attribute__((address_space(3))) void*)lp, 16, 0, 0);
  }
}

__global__ __launch_bounds__(256) void gemm_bf16(short* __restrict__ ws,
    const float* __restrict__ bq, const float* __restrict__ bk,
    const float* __restrict__ bv, const float* __restrict__ bo,
    float* __restrict__ out, int mode_base) {
  const int tid = threadIdx.x, lane = tid & 63, w = tid >> 6;
  const int wm = w >> 1, wn = w & 1;
  const int ln15 = lane & 15, g = lane >> 4;
  const int bm = blockIdx.y, bn = blockIdx.x;
  const int mode = (mode_base == 3) ? 3 : (int)blockIdx.z;

  const short* A; const short* Bt; const float* bias;
  if (mode == 0)      { A = ws + XQ_OFF;  Bt = ws + WQT_OFF; bias = bq; }
  else if (mode == 1) { A = ws + XK_OFF;  Bt = ws + WKT_OFF; bias = bk; }
  else if (mode == 2) { A = ws + XV_OFF;  Bt = ws + WVT_OFF; bias = bv; }
  else                { A = ws + CTX_OFF; Bt = ws + WOT_OFF; bias = bo; }

  __shared__ short smem[2][2][8192];   // [A/B][dbuf][128*64]
  short (*sA)[8192] = smem[0];
  short (*sB)[8192] = smem[1];

  f32x4 acc[4][4] = {};

  const short* Ab = A + (size_t)bm * 128 * 1024;
  const short* Bb = Bt + (size_t)bn * 128 * 1024;

  stage_tile(Ab, sA[0], w, lane);
  stage_tile(Bb, sB[0], w, lane);
  __syncthreads();

  int cur = 0;
#pragma unroll 1
  for (int kt = 0; kt < 16; ++kt) {
    if (kt < 15) {
      stage_tile(Ab + (kt + 1) * 64, sA[cur ^ 1], w, lane);
      stage_tile(Bb + (kt + 1) * 64, sB[cur ^ 1], w, lane);
    }
#pragma unroll
    for (int kk = 0; kk < 2; ++kk) {
      bf16x8 af[4], bfr[4];
#pragma unroll
      for (int m = 0; m < 4; ++m)
        af[m] = *(const bf16x8*)&sA[cur][(wm * 64 + m * 16 + ln15) * 64 + kk * 32 + g * 8];
#pragma unroll
      for (int n = 0; n < 4; ++n)
        bfr[n] = *(const bf16x8*)&sB[cur][(wn * 64 + n * 16 + ln15) * 64 + kk * 32 + g * 8];
#pragma unroll
      for (int m = 0; m < 4; ++m)
#pragma unroll
        for (int n = 0; n < 4; ++n)
          acc[m][n] = __builtin_amdgcn_mfma_f32_16x16x32_bf16(af[m], bfr[n], acc[m][n], 0, 0, 0);
    }
    __syncthreads();
    cur ^= 1;
  }

  float bb[4];
#pragma unroll
  for (int n = 0; n < 4; ++n) bb[n] = bias[bn * 128 + wn * 64 + n * 16 + ln15];

  if (mode == 3) {
#pragma unroll
    for (int m = 0; m < 4; ++m) {
      int row0 = bm * 128 + wm * 64 + m * 16 + g * 4;
#pragma unroll
      for (int n = 0; n < 4; ++n) {
        int col = bn * 128 + wn * 64 + n * 16 + ln15;
#pragma unroll
        for (int r = 0; r < 4; ++r)
          out[(size_t)(row0 + r) * 1024 + col] = acc[m][n][r] + bb[n];
      }
    }
    return;
  }

  float sc = (mode == 0) ? QSCALE : 1.0f;
  short (*tile)[136] = (short(*)[136])smem;  // 128x136 bf16
#pragma unroll
  for (int m = 0; m < 4; ++m)
#pragma unroll
    for (int n = 0; n < 4; ++n)
#pragma unroll
      for (int r = 0; r < 4; ++r)
        tile[wm * 64 + m * 16 + g * 4 + r][wn * 64 + n * 16 + ln15] =
            (short)f2b((acc[m][n][r] + bb[n]) * sc);
  __syncthreads();

  if (mode == 2) {
    // blocked vht: [bh][sblk(16)][hd(64)][s(128)]
    int dcol = tid >> 1, sh = (tid & 1) * 64;
    int colg = bn * 128 + dcol, h = colg >> 6, hd = colg & 63;
    int b = bm >> 4, sblk = bm & 15;
    short* dst = ws + VHT_OFF +
                 ((size_t)((b * 16 + h) * 16 + sblk)) * 8192 + hd * 128 + sh;
#pragma unroll
    for (int j = 0; j < 8; ++j) {
      u32x4 pk;
#pragma unroll
      for (int q = 0; q < 4; ++q) {
        unsigned lo = (unsigned short)tile[sh + j * 8 + q * 2][dcol];
        unsigned hi = (unsigned short)tile[sh + j * 8 + q * 2 + 1][dcol];
        pk[q] = lo | (hi << 16);
      }
      *(u32x4*)(dst + j * 8) = pk;
    }
  } else {
    int r = tid >> 1, sh = (tid & 1) * 64;
    int colg = bn * 128 + sh, h = colg >> 6;
    int sg = bm * 128 + r, b = sg >> 11, sl = sg & 2047;
    short* dst = ws + ((mode == 0) ? QH_OFF : KH_OFF) +
                 (((size_t)(b * 16 + h)) * 2048 + sl) * 64;
#pragma unroll
    for (int j = 0; j < 8; ++j)
      *(u32x4*)(dst + j * 8) = *(const u32x4*)&tile[r][sh + j * 8];
  }
}

// ---------------- K2: fused attention, GEMM-style LDS staging ----------
// r8 structure (best measured: 269us total). Block-level global_load_lds
// staging (XOR-swizzled source, linear LDS dest), 8 waves consume via
// ds_read_b128. Counted vmcnt(16) before raw s_barrier keeps the 16 attn
// stores in flight while draining the 2 older staging loads.
__global__ __launch_bounds__(512) void attn_k(short* __restrict__ ws,
                                              float* __restrict__ attn) {
  const int tid = threadIdx.x, lane = tid & 63, w = tid >> 6;  // 8 waves
  const int ln15 = lane & 15, g = lane >> 4;
  // XCD-affine swizzle: same-bh blocks land on the same XCD
  int bid = blockIdx.x;                  // 512 blocks
  int qt = (bid >> 3) & 15;              // 16 q-tiles of 128 rows
  int bh = (bid & 7) + 8 * (bid >> 7);   // 4 bh per XCD
  const int q0 = qt * 128;

  const short* Q  = ws + QH_OFF  + ((size_t)bh * 2048 + q0) * 64;
  const short* K  = ws + KH_OFF  + (size_t)bh * 2048 * 64;
  const short* Vt = ws + VHT_OFF + (size_t)bh * 131072;

  __shared__ short sK[2][4096];   // [64 k][64 d] bf16, XOR-swizzled chunks
  __shared__ short sV[2][4096];   // [64 hd][64 s] bf16, XOR-swizzled chunks
  __shared__ short Pl[128][72];   // P bf16, 144B row stride (16B-aligned)

  // staging decomposition: 512 threads x 16B = one 8KB tile per call.
  // LDS[row][c] = G[row][c ^ (row&7)]  (16B chunks; involution)
  const int srow = tid >> 3, sc = tid & 7;
  const int scsw = sc ^ (srow & 7);
  const int sdst = tid * 8;  // short offset; byte = tid*16

#define STAGE_K(kt, buf)                                                     \
  __builtin_amdgcn_global_load_lds(                                         \
      (const __attribute__((address_space(1))) void*)(K + ((kt) * 64 + srow) * 64 + scsw * 8), \
      (__attribute__((address_space(3))) void*)(&sK[buf][sdst]), 16, 0, 0)
#define STAGE_V(kt, buf)                                                     \
  __builtin_amdgcn_global_load_lds(                                         \
      (const __attribute__((address_space(1))) void*)(Vt + ((kt) >> 1) * 8192 + srow * 128 + ((kt) & 1) * 64 + scsw * 8), \
      (__attribute__((address_space(3))) void*)(&sV[buf][sdst]), 16, 0, 0)

  // Q fragments: wave w owns q rows [w*16, w*16+16)
  bf16x8 qf0 = *(const bf16x8*)&Q[(w * 16 + ln15) * 64 + g * 8];
  bf16x8 qf1 = *(const bf16x8*)&Q[(w * 16 + ln15) * 64 + 32 + g * 8];

  // ---- pass 1: softmax denominators ----
  STAGE_K(0, 0);
  asm volatile("s_waitcnt vmcnt(0)" ::: "memory");
  __builtin_amdgcn_s_barrier();

  float ps0 = 0.f, ps1 = 0.f;
  int cur = 0;
#pragma unroll 1
  for (int kt = 0; kt < 32; ++kt) {
    if (kt < 31) STAGE_K(kt + 1, cur ^ 1);
#pragma unroll
    for (int m = 0; m < 4; ++m) {
      int r = m * 16 + ln15;
      bf16x8 ka0 = *(const bf16x8*)&sK[cur][r * 64 + ((g ^ (r & 7)) * 8)];
      bf16x8 ka1 = *(const bf16x8*)&sK[cur][r * 64 + (((4 + g) ^ (r & 7)) * 8)];
      f32x4 c = {0.f, 0.f, 0.f, 0.f};
      c = __builtin_amdgcn_mfma_f32_16x16x32_bf16(ka0, qf0, c, 0, 0, 0);
      c = __builtin_amdgcn_mfma_f32_16x16x32_bf16(ka1, qf1, c, 0, 0, 0);
      ps0 += EXP2(c[0]) + EXP2(c[1]);
      ps1 += EXP2(c[2]) + EXP2(c[3]);
    }
    asm volatile("s_waitcnt vmcnt(0)" ::: "memory");
    __builtin_amdgcn_s_barrier();
    cur ^= 1;
  }
  float ps = ps0 + ps1;
  ps += __shfl_xor(ps, 16, 64);  // reduce the 4 k-groups (same q col)
  ps += __shfl_xor(ps, 32, 64);
  float ri = 1.0f / ps;

  // ---- pass 2: QK^T -> P (LDS) -> PV + attn stores ----
  STAGE_K(0, 0);
  STAGE_V(0, 0);
  asm volatile("s_waitcnt vmcnt(0)" ::: "memory");
  __builtin_amdgcn_s_barrier();

  f32x4 cacc[4] = {};
  cur = 0;
#pragma unroll 1
  for (int kt = 0; kt < 32; ++kt) {
    if (kt < 31) {
      STAGE_K(kt + 1, cur ^ 1);
      STAGE_V(kt + 1, cur ^ 1);
    }
    // QK^T (swapped): lane holds P[q=ln15][k=m*16+g*4+r]
#pragma unroll
    for (int m = 0; m < 4; ++m) {
      int r = m * 16 + ln15;
      bf16x8 ka0 = *(const bf16x8*)&sK[cur][r * 64 + ((g ^ (r & 7)) * 8)];
      bf16x8 ka1 = *(const bf16x8*)&sK[cur][r * 64 + (((4 + g) ^ (r & 7)) * 8)];
      f32x4 c = {0.f, 0.f, 0.f, 0.f};
      c = __builtin_amdgcn_mfma_f32_16x16x32_bf16(ka0, qf0, c, 0, 0, 0);
      c = __builtin_amdgcn_mfma_f32_16x16x32_bf16(ka1, qf1, c, 0, 0, 0);
      bf16x4 pb;
      pb[0] = (__bf16)(EXP2(c[0]) * ri);
      pb[1] = (__bf16)(EXP2(c[1]) * ri);
      pb[2] = (__bf16)(EXP2(c[2]) * ri);
      pb[3] = (__bf16)(EXP2(c[3]) * ri);
      *(bf16x4*)&Pl[w * 16 + ln15][m * 16 + g * 4] = pb;
    }
    asm volatile("s_waitcnt lgkmcnt(0)" ::: "memory");  // own P writes visible
    __builtin_amdgcn_sched_barrier(0);                  // rule #18 fence

    // PV: ctx[q][hd] += P[q][k] * V[k][hd]
#pragma unroll
    for (int kk = 0; kk < 2; ++kk) {
      bf16x8 pa = *(const bf16x8*)&Pl[w * 16 + ln15][kk * 32 + g * 8];
#pragma unroll
      for (int n = 0; n < 4; ++n) {
        int vr = n * 16 + ln15;
        bf16x8 vb =
            *(const bf16x8*)&sV[cur][vr * 64 + (((kk * 4 + g) ^ (vr & 7)) * 8)];
        cacc[n] = __builtin_amdgcn_mfma_f32_16x16x32_bf16(pa, vb, cacc[n], 0, 0, 0);
      }
    }

    // attn stores: 16 rows x 256B (cached; L2 coalesces)
    float* ab = attn + ((size_t)(bh * 2048 + q0 + w * 16)) * 2048 + kt * 64 + lane;
#pragma unroll
    for (int r = 0; r < 16; ++r) {
      unsigned short u = (unsigned short)Pl[w * 16 + r][lane];
      ab[(size_t)r * 2048] = b2f(u);
    }

    // drain the 2 staging loads (older), leave the 16 stores in flight
    asm volatile("s_waitcnt vmcnt(16)" ::: "memory");
    __builtin_amdgcn_s_barrier();
    cur ^= 1;
  }

  // ctx epilogue -> (B,S,D) bf16, repacked via own Pl slice to 128B rows
  {
    short* Pw = &Pl[w * 16][0];
#pragma unroll
    for (int n = 0; n < 4; ++n)
#pragma unroll
      for (int r = 0; r < 4; ++r)
        Pw[(g * 4 + r) * 72 + n * 16 + ln15] = (short)f2b(cacc[n][r]);
    asm volatile("s_waitcnt lgkmcnt(0)" ::: "memory");
    __builtin_amdgcn_sched_barrier(0);
    int b = bh >> 4, h = bh & 15;
    int row = lane >> 3, col = (lane & 7) * 8;
#pragma unroll
    for (int i = 0; i < 2; ++i) {
      int q = q0 + w * 16 + i * 8 + row;
      u32x4 pk = *(const u32x4*)&Pw[(i * 8 + row) * 72 + col];
      *(u32x4*)&ws[CTX_OFF + ((size_t)(b * 2048 + q)) * 1024 + h * 64 + col] = pk;
    }
  }
#undef STAGE_K
#undef STAGE_V
}

extern "C" void kernel_launch(void* const* d_in, const int* in_sizes, int n_in,
                              void* d_out, int out_size, void* d_ws, size_t ws_size,
                              hipStream_t stream) {
  const float* q  = (const float*)d_in[0];
  const float* k  = (const float*)d_in[1];
  const float* v  = (const float*)d_in[2];
  const float* wq = (const float*)d_in[3];
  const float* bq = (const float*)d_in[4];
  const float* wk = (const float*)d_in[5];
  const float* bk = (const float*)d_in[6];
  const float* wv = (const float*)d_in[7];
  const float* bv = (const float*)d_in[8];
  const float* wo = (const float*)d_in[9];
  const float* bo = (const float*)d_in[10];
  float* out  = (float*)d_out;
  float* attn = out + 4194304;  // out (2,2048,1024) then attn (2,16,2048,2048)
  short* ws = (short*)d_ws;
  if (ws_size < WS_BYTES) return;  // need 64 MB scratch

  cvt_qkv<<<dim3(4096, 3), 256, 0, stream>>>(q, k, v, ws);
  cvt_wt<<<dim3(32, 32, 4), dim3(32, 8), 0, stream>>>(wq, wk, wv, wo, ws);
  gemm_bf16<<<dim3(8, 32, 3), 256, 0, stream>>>(ws, bq, bk, bv, bo, out, 0);
  attn_k<<<dim3(512), 512, 0, stream>>>(ws, attn);
  gemm_bf16<<<dim3(8, 32, 1), 256, 0, stream>>>(ws, bq, bk, bv, bo, out, 3);
}